// Round 14
// baseline (5057.425 us; speedup 1.0000x reference)
//
#include <hip/hip_runtime.h>
#include <math.h>

#define TT 2048
#define BB 32
#define HH 512

// clang native vector types for nontemporal builtins (HIP_vector_type is rejected)
typedef float f32x4 __attribute__((ext_vector_type(4)));
typedef float f32x2 __attribute__((ext_vector_type(2)));

// ---------------- input-projection GEMM: OUT[r,:] = X[r,:]@W + bias ----------------
// nt hints: x is read once, pre0 is written once (and only re-read ~ms later, far
// beyond L2 lifetime) -> keep both out of L2 so the recurrence's hb lines survive.
template<int K>
__global__ void __launch_bounds__(256)
ih_gemm(const float* X, const float* __restrict__ W,
        const float* __restrict__ bias, float* OUT)
{
    __shared__ float xt[32][K];
    const int wg  = (int)blockIdx.x;
    const int tid = (int)threadIdx.x;
    const long row0 = (long)wg * 32;

    {   // stage 32 rows of X (coalesced 16B, non-temporal)
        const f32x4* Xv = (const f32x4*)(X + row0 * K);
        f32x4* xtv = (f32x4*)(&xt[0][0]);
        const int n4 = 8 * K;
        for (int i = tid; i < n4; i += 256) xtv[i] = __builtin_nontemporal_load(&Xv[i]);
    }
    __syncthreads();

    const int j2 = tid * 2;
    float acc0[32], acc1[32];
    #pragma unroll
    for (int r = 0; r < 32; ++r) { acc0[r] = 0.f; acc1[r] = 0.f; }

    for (int k = 0; k < K; k += 4) {
        const float2 w0 = *(const float2*)&W[(k+0)*HH + j2];
        const float2 w1 = *(const float2*)&W[(k+1)*HH + j2];
        const float2 w2 = *(const float2*)&W[(k+2)*HH + j2];
        const float2 w3 = *(const float2*)&W[(k+3)*HH + j2];
        #pragma unroll
        for (int r = 0; r < 32; ++r) {
            const float4 xv = *(const float4*)&xt[r][k];
            acc0[r] += xv.x*w0.x + xv.y*w1.x + xv.z*w2.x + xv.w*w3.x;
            acc1[r] += xv.x*w0.y + xv.y*w1.y + xv.z*w2.y + xv.w*w3.y;
        }
    }
    const float2 bv = *(const float2*)&bias[j2];
    #pragma unroll
    for (int r = 0; r < 32; ++r) {
        f32x2 o; o.x = acc0[r] + bv.x; o.y = acc1[r] + bv.y;
        __builtin_nontemporal_store(o, (f32x2*)&OUT[(row0 + r) * HH + j2]);
    }
}

// ---------------- fused 2-layer persistent recurrence ----------------
// r12 structure (PASSED; schedule/tag-chain/parity-LDS proofs unchanged) plus:
//  (1) nt loads/stores on pre0/h1/hT streams -> hb stays L2-resident, poll RTT
//      drops from HBM (~900cy, r12 evidence: WRITE_SIZE == all stores) to L2.
//  (2) h broadcast via LDS instead of readlane: each wave ds_writes its polled
//      h-slice to a wave-PRIVATE lds_h region (same-wave RAW -> lgkmcnt, no
//      barrier), then 16 uniform-address ds_read_b128 deliver h to all lanes
//      (broadcast = conflict-free). Kills 192 readlane/superstep: C1-critical
//      MAC = 64 fma only.
static __device__ __forceinline__ float tanhx(float s) {
    const float e = __expf(2.0f * s);
    return 1.0f - 2.0f / (e + 1.0f);
}
static __device__ __forceinline__ void pub(unsigned long long* p, unsigned tag, float v) {
    __hip_atomic_store(p, ((unsigned long long)tag << 32) | (unsigned long long)__float_as_uint(v),
                       __ATOMIC_RELAXED, __HIP_MEMORY_SCOPE_AGENT);
}
static __device__ __forceinline__ float pollv(unsigned long long* p, unsigned want) {
    unsigned long long pk = __hip_atomic_load(p, __ATOMIC_RELAXED, __HIP_MEMORY_SCOPE_AGENT);
    while ((unsigned)(pk >> 32) != want)
        pk = __hip_atomic_load(p, __ATOMIC_RELAXED, __HIP_MEMORY_SCOPE_AGENT);
    return __uint_as_float((unsigned)(pk & 0xffffffffu));
}

__global__ void __attribute__((amdgpu_flat_work_group_size(512, 512),
                               amdgpu_waves_per_eu(2, 2)))
fused_recur(const float* __restrict__ Whh0, const float* __restrict__ Wih1,
            const float* __restrict__ Whh1, const float* __restrict__ b1,
            float* __restrict__ seq, float* __restrict__ hTout,
            unsigned long long* __restrict__ hb0, unsigned long long* __restrict__ hb1)
{
    __shared__ float lds_w[HH][64];        // Whh1 slice: [k][j-local], 128 KB
    __shared__ float lds_a[2][8][64];      // C1 partials (parity dbuf)
    __shared__ float lds_b[2][8][64];      // C2 partials (parity dbuf)
    __shared__ float lds_h0[HH];           // h0 broadcast, wave-private 64-slices
    __shared__ float lds_h1[HH];           // h1 broadcast, wave-private 64-slices
    const int bid  = (int)blockIdx.x;
    const int c    = bid & 31;      // chain; 8 WGs of chain c share bid%8 -> same XCD
    const int x    = bid >> 5;      // col-slice 0..7
    const int tid  = (int)threadIdx.x;
    const int lane = tid & 63;
    const int w    = tid >> 6;      // wave id == k-group
    const int J    = (x << 6) + lane;
    const long wb  = (long)(w << 6) * HH + J;   // &M[(w*64+kk)*HH + J], kk stride HH

    // ---- stage Whh1 slice into LDS (one-time, coalesced float4) ----
    {
        const int x64 = x << 6;
        for (int idx = tid; idx < HH * 16; idx += 512) {   // 16 float4 per k-row
            const int k  = idx >> 4;
            const int j4 = (idx & 15) << 2;
            *(float4*)&lds_w[k][j4] = *(const float4*)&Whh1[(long)k * HH + x64 + j4];
        }
    }

    // ---- Whh0 (wa*) + Wih1 (wi*): 32 named float4s, pinned arch VGPRs ----
    float4 wa0,wa1,wa2,wa3,wa4,wa5,wa6,wa7,wa8,wa9,wa10,wa11,wa12,wa13,wa14,wa15;
    float4 wi0,wi1,wi2,wi3,wi4,wi5,wi6,wi7,wi8,wi9,wi10,wi11,wi12,wi13,wi14,wi15;
#define LD1(P, M, q) do { \
        P##q.x = M[wb + (4*q+0)*HH]; P##q.y = M[wb + (4*q+1)*HH]; \
        P##q.z = M[wb + (4*q+2)*HH]; P##q.w = M[wb + (4*q+3)*HH]; } while (0)
    LD1(wa,Whh0,0);  LD1(wa,Whh0,1);  LD1(wa,Whh0,2);  LD1(wa,Whh0,3);
    LD1(wa,Whh0,4);  LD1(wa,Whh0,5);  LD1(wa,Whh0,6);  LD1(wa,Whh0,7);
    LD1(wa,Whh0,8);  LD1(wa,Whh0,9);  LD1(wa,Whh0,10); LD1(wa,Whh0,11);
    LD1(wa,Whh0,12); LD1(wa,Whh0,13); LD1(wa,Whh0,14); LD1(wa,Whh0,15);
    LD1(wi,Wih1,0);  LD1(wi,Wih1,1);  LD1(wi,Wih1,2);  LD1(wi,Wih1,3);
    LD1(wi,Wih1,4);  LD1(wi,Wih1,5);  LD1(wi,Wih1,6);  LD1(wi,Wih1,7);
    LD1(wi,Wih1,8);  LD1(wi,Wih1,9);  LD1(wi,Wih1,10); LD1(wi,Wih1,11);
    LD1(wi,Wih1,12); LD1(wi,Wih1,13); LD1(wi,Wih1,14); LD1(wi,Wih1,15);
#undef LD1
#define PIN1(P, q) asm volatile("" : "+v"(P##q.x), "+v"(P##q.y), "+v"(P##q.z), "+v"(P##q.w))
    PIN1(wa,0);  PIN1(wa,1);  PIN1(wa,2);  PIN1(wa,3);
    PIN1(wa,4);  PIN1(wa,5);  PIN1(wa,6);  PIN1(wa,7);
    PIN1(wa,8);  PIN1(wa,9);  PIN1(wa,10); PIN1(wa,11);
    PIN1(wa,12); PIN1(wa,13); PIN1(wa,14); PIN1(wa,15);
    PIN1(wi,0);  PIN1(wi,1);  PIN1(wi,2);  PIN1(wi,3);
    PIN1(wi,4);  PIN1(wi,5);  PIN1(wi,6);  PIN1(wi,7);
    PIN1(wi,8);  PIN1(wi,9);  PIN1(wi,10); PIN1(wi,11);
    PIN1(wi,12); PIN1(wi,13); PIN1(wi,14); PIN1(wi,15);
#undef PIN1

    unsigned long long* hbc0 = hb0 + c * (2 * HH);   // [2][512] packed {tag|val}
    unsigned long long* hbc1 = hb1 + c * (2 * HH);
    float* rowbase = seq + (long)c * TT * HH;        // pre0 in, h1 out (in-place)

    float pre_cur = 0.f, b1v = 0.f;
    if (tid < 64) { pre_cur = __builtin_nontemporal_load(&rowbase[J]); b1v = b1[J]; }

    __syncthreads();   // lds_w staged before first C2

    // prologue: h0[0] = tanh(pre0[0]); publish tag 1 (slot 0)
    if (tid < 64) {
        const float hv = tanhx(pre_cur);
        pub(hbc0 + J, 1u, hv);
        pre_cur = __builtin_nontemporal_load(&rowbase[HH + J]);   // pre0[1]
    }
    float h1reg = 0.f;
    const float*  lwcol = &lds_w[w << 6][lane];              // my k-block column in LDS
    const float4* h0v   = (const float4*)&lds_h0[w << 6];    // wave-private h0 slice
    const float4* h1v4  = (const float4*)&lds_h1[w << 6];    // wave-private h1 slice

    for (int t = 0; t < TT; ++t) {
        // P3: poll h0[t] (tag t+1, slot t&1) — the one real RTT wait per super-step
        const float h0new = pollv(hbc0 + ((t & 1) << 9) + (w << 6) + lane, (unsigned)(t + 1));
        lds_h0[(w << 6) + lane] = h0new;    // wave-private; same-wave RAW via lgkmcnt

        if (t + 1 < TT) {   // C1: layer-0 step — the critical chain (64 fma, no readlane)
            float a0 = 0.f, a1 = 0.f, a2 = 0.f, a3 = 0.f;
#define MACA(q) do { const float4 h4 = h0v[q]; \
                     a0 = fmaf(h4.x, wa##q.x, a0); a1 = fmaf(h4.y, wa##q.y, a1); \
                     a2 = fmaf(h4.z, wa##q.z, a2); a3 = fmaf(h4.w, wa##q.w, a3); } while (0)
            MACA(0); MACA(1); MACA(2); MACA(3); MACA(4); MACA(5); MACA(6); MACA(7);
            MACA(8); MACA(9); MACA(10); MACA(11); MACA(12); MACA(13); MACA(14); MACA(15);
#undef MACA
            lds_a[(t + 1) & 1][w][lane] = (a0 + a1) + (a2 + a3);
            __syncthreads();
            if (tid < 64) {
                float s = pre_cur;
                #pragma unroll
                for (int q = 0; q < 8; ++q) s += lds_a[(t + 1) & 1][q][lane];
                const float hv = tanhx(s);
                pub(hbc0 + (((t + 1) & 1) << 9) + J, (unsigned)(t + 2), hv);  // publish ASAP
                if (t + 2 < TT) pre_cur = __builtin_nontemporal_load(&rowbase[(long)(t + 2) * HH + J]);
                if (t + 1 == TT - 1) __builtin_nontemporal_store(hv, &hTout[(c << 9) + J]);
            }
        }

        // P2: poll h1[t-1] (tag t, slot (t-1)&1) — published a full super-step ago
        if (t > 0)
            h1reg = pollv(hbc1 + (((t - 1) & 1) << 9) + (w << 6) + lane, (unsigned)t);
        lds_h1[(w << 6) + lane] = h1reg;

        // C2: layer-1 step. h0/h1 via LDS uniform-b128 broadcast; Wih1 from regs,
        // Whh1 from LDS (poll-independent reads pipeline ahead).
        {
            float a0 = 0.f, a1 = 0.f, a2 = 0.f, a3 = 0.f;
#define MACI(q) do { const float4 h4 = h0v[q]; \
                     a0 = fmaf(h4.x, wi##q.x, a0); a1 = fmaf(h4.y, wi##q.y, a1); \
                     a2 = fmaf(h4.z, wi##q.z, a2); a3 = fmaf(h4.w, wi##q.w, a3); } while (0)
#define MACH(q) do { const float4 h4 = h1v4[q]; \
            a0 = fmaf(h4.x, lwcol[(4*q+0)*64], a0); \
            a1 = fmaf(h4.y, lwcol[(4*q+1)*64], a1); \
            a2 = fmaf(h4.z, lwcol[(4*q+2)*64], a2); \
            a3 = fmaf(h4.w, lwcol[(4*q+3)*64], a3); } while (0)
            MACI(0); MACI(1); MACI(2); MACI(3); MACI(4); MACI(5); MACI(6); MACI(7);
            MACI(8); MACI(9); MACI(10); MACI(11); MACI(12); MACI(13); MACI(14); MACI(15);
            MACH(0); MACH(1); MACH(2); MACH(3); MACH(4); MACH(5); MACH(6); MACH(7);
            MACH(8); MACH(9); MACH(10); MACH(11); MACH(12); MACH(13); MACH(14); MACH(15);
#undef MACH
#undef MACI
            lds_b[t & 1][w][lane] = (a0 + a1) + (a2 + a3);
            __syncthreads();
            if (tid < 64) {
                float s2 = b1v;
                #pragma unroll
                for (int q = 0; q < 8; ++q) s2 += lds_b[t & 1][q][lane];
                const float h1v = tanhx(s2);
                __builtin_nontemporal_store(h1v, &rowbase[(long)t * HH + J]);  // output
                if (t + 1 < TT) pub(hbc1 + ((t & 1) << 9) + J, (unsigned)(t + 1), h1v);
                else __builtin_nontemporal_store(h1v, &hTout[(BB << 9) + (c << 9) + J]);
            }
        }
    }
}

extern "C" void kernel_launch(void* const* d_in, const int* in_sizes, int n_in,
                              void* d_out, int out_size, void* d_ws, size_t ws_size,
                              hipStream_t stream) {
    const float* x    = (const float*)d_in[0];
    const float* Wih0 = (const float*)d_in[1];
    const float* Whh0 = (const float*)d_in[2];
    const float* b0   = (const float*)d_in[3];
    const float* Wih1 = (const float*)d_in[4];
    const float* Whh1 = (const float*)d_in[5];
    const float* b1   = (const float*)d_in[6];

    float* out = (float*)d_out;                       // [B,T,H] (h1 seq) + [2,B,H] (hT)
    float* hT  = out + (size_t)BB * TT * HH;

    // ws: hb0 [32][2][512]x8B = 256K, hb1 same at +256K. memset both each call:
    // graph replays reuse ws un-poisoned and stale tags would alias wanted tags.
    unsigned long long* hb0 = (unsigned long long*)d_ws;
    unsigned long long* hb1 = hb0 + (size_t)BB * 2 * HH;
    (void)hipMemsetAsync(d_ws, 0, (size_t)2 * BB * 2 * HH * sizeof(unsigned long long), stream);

    // 1) pre0 = x @ W_ih0 + b0  -> d_out main region (consumed in-place by fused_recur)
    ih_gemm<256><<<dim3((BB * TT) / 32), dim3(256), 0, stream>>>(x, Wih0, b0, out);
    // 2) fused 2-layer recurrence: h1 seq -> d_out (in-place over pre0), hT tails
    fused_recur<<<dim3(256), dim3(512), 0, stream>>>(Whh0, Wih1, Whh1, b1,
                                                     out, hT, hb0, hb1);
}